// Round 18
// baseline (579.337 us; speedup 1.0000x reference)
//
#include <hip/hip_runtime.h>
#include <hip/hip_fp16.h>

#define DEVI __device__ __forceinline__

typedef short v8s __attribute__((ext_vector_type(8)));
typedef float v4f __attribute__((ext_vector_type(4)));
typedef _Float16 h2v __attribute__((ext_vector_type(2)));
typedef __fp16 fp16x2 __attribute__((ext_vector_type(2)));
typedef unsigned short u16;

typedef __attribute__((address_space(3))) unsigned int lds_u32;
typedef const __attribute__((address_space(1))) unsigned int glb_u32;

DEVI float bf2f(short s) {
  union { unsigned u; float f; } cv;
  cv.u = ((unsigned)(u16)s) << 16;
  return cv.f;
}
DEVI short f2bf(float f) {
  union { float f; unsigned u; } cv; cv.f = f;
  unsigned u = cv.u;
  return (short)((u + 0x7FFFu + ((u >> 16) & 1u)) >> 16);
}
DEVI unsigned cvtpk(float lo, float hi) {  // packed bf16 [hi|lo], RNE (proven R14)
  unsigned r;
  asm("v_cvt_pk_bf16_f32 %0, %1, %2" : "=v"(r) : "v"(lo), "v"(hi));
  return r;
}
DEVI unsigned pkh(float a, float b) {      // packed f16 [b|a], RTZ
  union { fp16x2 h; unsigned u; } cv;
  cv.h = __builtin_amdgcn_cvt_pkrtz(a, b);
  return cv.u;
}
DEVI float fdot2u(unsigned a, unsigned b, float c) {  // f16 dot2, f32 accum (proven R17)
  union { unsigned u; h2v h; } ca, cb; ca.u = a; cb.u = b;
  return __builtin_amdgcn_fdot2(ca.h, cb.h, c, false);
}
DEVI __half2 uh2(unsigned u) { union { unsigned u; __half2 h; } c; c.u = u; return c.h; }
DEVI void gld16(const void* g, void* l) {
  __builtin_amdgcn_global_load_lds((glb_u32*)g, (lds_u32*)l, 16, 0, 0);
}

// ---------------- prep: transpose + cast weights to bf16 ----------------
__global__ void prep_weights(const float* __restrict__ Wq, const float* __restrict__ Wk,
                             const float* __restrict__ Wv, const float* __restrict__ Wout,
                             short* __restrict__ WcT, short* __restrict__ WoT) {
  int n = blockIdx.x;
  int k = threadIdx.x;
  float v;
  if (n < 256)      v = Wq[k * 256 + n];
  else if (n < 512) v = Wk[k * 256 + (n - 256)];
  else              v = Wv[k * 256 + (n - 512)];
  WcT[n * 256 + k] = f2bf(v);
  if (n < 256) WoT[n * 256 + k] = f2bf(Wout[k * 256 + n]);
}

// ---------------- x -> bf16 cast ----------------
__global__ void x_cast(const float* __restrict__ x, short* __restrict__ xb) {
  for (size_t gidx = (size_t)blockIdx.x * 256 + threadIdx.x; gidx < 4194304;
       gidx += (size_t)4096 * 256) {
    const float4* src = reinterpret_cast<const float4*>(x + gidx * 8);
    float4 a = src[0], c = src[1];
    v8s pk;
    pk[0] = f2bf(a.x); pk[1] = f2bf(a.y); pk[2] = f2bf(a.z); pk[3] = f2bf(a.w);
    pk[4] = f2bf(c.x); pk[5] = f2bf(c.y); pk[6] = f2bf(c.z); pk[7] = f2bf(c.w);
    *reinterpret_cast<v8s*>(xb + gidx * 8) = pk;
  }
}

// ---------------- QKV projection: 256x256 tile, swapped-operand MFMA, wide stores ----------------
// Q/K/V all emitted as packed f16 (attn consumes via fdot2 / pk_fma).
__launch_bounds__(512, 2)
__global__ void proj_gemm(const short* __restrict__ xb, const short* __restrict__ WcT,
                          const float* __restrict__ pos_emb,
                          short* __restrict__ Qb, short* __restrict__ Kb,
                          short* __restrict__ Vb) {
  __shared__ short As[2][256 * 64];
  __shared__ short Bs[2][256 * 64];
  const int t = threadIdx.x;
  const int bi = blockIdx.x;
  const int xcd = bi & 7;
  const int j = bi >> 3;               // 0..191
  const int mtl = j / 3, nt = j % 3;
  const int mt = xcd * 64 + mtl;       // 0..511, bijective
  const int m0 = mt * 256, n0 = nt * 256;
  const int wave = t >> 6, lane = t & 63;
  const int wm = (wave >> 2) * 128, wn = (wave & 3) * 64;
  const int lr = lane & 15, g = lane >> 4;

  const int ro = lane >> 3;
  const int colb = ((lane & 7) * 16) ^ (ro << 4);
  const char* aSrc0 = reinterpret_cast<const char*>(xb + (size_t)(m0 + ro) * 256) + colb;
  const char* bSrc0 = reinterpret_cast<const char*>(WcT + (size_t)(n0 + ro) * 256) + colb;

  auto stage = [&](int buf, int ks) {
#pragma unroll
    for (int c = 0; c < 4; ++c) {
      int cc = wave * 4 + c;
      gld16(aSrc0 + (size_t)cc * 8 * 512 + ks * 128, (char*)As[buf] + cc * 1024);
      gld16(bSrc0 + (size_t)cc * 8 * 512 + ks * 128, (char*)Bs[buf] + cc * 1024);
    }
  };

  v4f acc[8][4];
#pragma unroll
  for (int i = 0; i < 8; ++i)
#pragma unroll
    for (int jj = 0; jj < 4; ++jj) acc[i][jj] = (v4f){0.f, 0.f, 0.f, 0.f};

  stage(0, 0);
  __syncthreads();

#pragma unroll 1
  for (int s = 0; s < 4; ++s) {
    const int buf = s & 1;
    if (s < 3) stage(buf ^ 1, s + 1);

    const char* aB = (const char*)As[buf];
    const char* bB = (const char*)Bs[buf];
#pragma unroll
    for (int kk = 0; kk < 2; ++kk) {
      v8s bfr[4];
#pragma unroll
      for (int jj = 0; jj < 4; ++jj) {
        int rn = wn + jj * 16 + lr;
        bfr[jj] = *reinterpret_cast<const v8s*>(
            bB + ((rn * 128 + kk * 64 + g * 16) ^ ((rn & 7) << 4)));
      }
#pragma unroll
      for (int i = 0; i < 8; ++i) {
        int row = wm + i * 16 + lr;
        v8s af = *reinterpret_cast<const v8s*>(
            aB + ((row * 128 + kk * 64 + g * 16) ^ ((row & 7) << 4)));
#pragma unroll
        for (int jj = 0; jj < 4; ++jj)
          acc[i][jj] = __builtin_amdgcn_mfma_f32_16x16x32_bf16(bfr[jj], af, acc[i][jj], 0, 0, 0);
      }
    }
    __syncthreads();
  }

  short* dst = (nt == 0) ? Qb : (nt == 1) ? Kb : Vb;
#pragma unroll
  for (int i = 0; i < 8; ++i) {
    int p = m0 + wm + i * 16 + lr;
    int qi = 0;
    if (nt == 0) {
      int yy = (p >> 7) & 127, xx = p & 127;
      qi = (yy - min(max(yy, 2), 125) + 2) * 5 + (xx - min(max(xx, 2), 125) + 2);
    }
#pragma unroll
    for (int jj = 0; jj < 4; ++jj) {
      int nb = wn + jj * 16 + g * 4;
      v4f a = acc[i][jj];
      if (nt == 0) {
        float4 pe4 = *reinterpret_cast<const float4*>(pos_emb + qi * 256 + nb);
        a[0] += pe4.x; a[1] += pe4.y; a[2] += pe4.z; a[3] += pe4.w;
      }
      uint2 pk;
      pk.x = pkh(a[0], a[1]);
      pk.y = pkh(a[2], a[3]);
      *reinterpret_cast<uint2*>(dst + (size_t)p * 256 + nb) = pk;
    }
  }
}

// ---------------- attention: full-head packed-f16 datapath ----------------
// thread = (pos, head); 32 fdot2 (QK + pe) + 16 pk_fma (V) per offset; no shfl.
__launch_bounds__(256, 2)
__global__ void attn_kernel(const short* __restrict__ Qb, const short* __restrict__ Kb,
                            const short* __restrict__ Vb, const float* __restrict__ pos_emb,
                            short* __restrict__ ACC) {
  __shared__ __align__(16) unsigned pe16[25 * 128];  // packed f16; rd-field XOR swizzle
  for (int i = threadIdx.x; i < 1600; i += 256) {
    float4 vv = reinterpret_cast<const float4*>(pos_emb)[i];
    int s = i >> 6;
    int jw = (i & 63) * 2;   // word index within row (even)
    int swz = (jw & ~15) | ((((jw >> 2) ^ (jw >> 5)) & 3) << 2) | (jw & 3);
    uint2 pk2;
    pk2.x = pkh(vv.x, vv.y);
    pk2.y = pkh(vv.z, vv.w);
    *reinterpret_cast<uint2*>(pe16 + s * 128 + swz) = pk2;
  }

  const int t = threadIdx.x;
  const int h = t & 7, pl = t >> 3;
  const int id = blockIdx.x;
  const int b = id & 7;                 // batch -> XCD
  const int local = id >> 3;            // 0..511
  const int bx = local & 31, by = local >> 5;   // 32 x-tiles(4) x 16 y-tiles(8)
  const int xx = bx * 4 + (pl & 3);
  const int yy = by * 8 + (pl >> 2);
  const int yc = min(max(yy, 2), 125), xc = min(max(xx, 2), 125);
  const int fo = h * 32;
  const size_t pbase = ((size_t)((b * 128 + yy) * 128 + xx)) * 256 + fo;
  const size_t cbase = ((size_t)((b * 128 + yc) * 128 + xc)) * 256 + fo;
  const float SCALE2 = 0.17677669529663689f * 1.4426950408889634f;

  // Q: 32 f16 = 4 uint4, kept packed
  uint4 q0 = *reinterpret_cast<const uint4*>(Qb + pbase);
  uint4 q1 = *reinterpret_cast<const uint4*>(Qb + pbase + 8);
  uint4 q2 = *reinterpret_cast<const uint4*>(Qb + pbase + 16);
  uint4 q3 = *reinterpret_cast<const uint4*>(Qb + pbase + 24);
  __syncthreads();

  // pe slice phys uint4 offsets for this head (inverse of staging swizzle)
  const unsigned* peb = pe16 + h * 16;
  const int hs = (h >> 1) & 3;
  const int r0 = ((0 ^ hs) & 3) * 4;
  const int r1 = ((1 ^ hs) & 3) * 4;
  const int r2 = ((2 ^ hs) & 3) * 4;
  const int r3 = ((3 ^ hs) & 3) * 4;

  float l = 0.f;
  __half2 oa[16];
#pragma unroll
  for (int j = 0; j < 16; ++j) oa[j] = uh2(0u);

  const short* kb = Kb + cbase;
  const short* vb = Vb + cbase;

#pragma unroll 1
  for (int dy = -2; dy <= 2; ++dy) {
    const short* krow = kb + dy * (128 * 256);
    const short* vrow = vb + dy * (128 * 256);
    const unsigned* perow = peb + ((dy + 2) * 5) * 128;
#pragma unroll
    for (int dxi = 0; dxi < 5; ++dxi) {
      const short* kp = krow + (dxi - 2) * 256;
      const short* vp = vrow + (dxi - 2) * 256;
      uint4 k0 = *reinterpret_cast<const uint4*>(kp);
      uint4 k1 = *reinterpret_cast<const uint4*>(kp + 8);
      uint4 k2 = *reinterpret_cast<const uint4*>(kp + 16);
      uint4 k3 = *reinterpret_cast<const uint4*>(kp + 24);
      uint4 v0 = *reinterpret_cast<const uint4*>(vp);
      uint4 v1 = *reinterpret_cast<const uint4*>(vp + 8);
      uint4 v2 = *reinterpret_cast<const uint4*>(vp + 16);
      uint4 v3 = *reinterpret_cast<const uint4*>(vp + 24);
      const unsigned* ps = perow + dxi * 128;
      uint4 p0 = *reinterpret_cast<const uint4*>(ps + r0);
      uint4 p1 = *reinterpret_cast<const uint4*>(ps + r1);
      uint4 p2 = *reinterpret_cast<const uint4*>(ps + r2);
      uint4 p3 = *reinterpret_cast<const uint4*>(ps + r3);

      float d0 = 0.f, d1 = 0.f, d2 = 0.f, d3 = 0.f;
      d0 = fdot2u(q0.x, k0.x, d0); d1 = fdot2u(q0.y, k0.y, d1);
      d2 = fdot2u(q0.z, k0.z, d2); d3 = fdot2u(q0.w, k0.w, d3);
      d0 = fdot2u(q1.x, k1.x, d0); d1 = fdot2u(q1.y, k1.y, d1);
      d2 = fdot2u(q1.z, k1.z, d2); d3 = fdot2u(q1.w, k1.w, d3);
      d0 = fdot2u(q2.x, k2.x, d0); d1 = fdot2u(q2.y, k2.y, d1);
      d2 = fdot2u(q2.z, k2.z, d2); d3 = fdot2u(q2.w, k2.w, d3);
      d0 = fdot2u(q3.x, k3.x, d0); d1 = fdot2u(q3.y, k3.y, d1);
      d2 = fdot2u(q3.z, k3.z, d2); d3 = fdot2u(q3.w, k3.w, d3);
      d0 = fdot2u(q0.x, p0.x, d0); d1 = fdot2u(q0.y, p0.y, d1);
      d2 = fdot2u(q0.z, p0.z, d2); d3 = fdot2u(q0.w, p0.w, d3);
      d0 = fdot2u(q1.x, p1.x, d0); d1 = fdot2u(q1.y, p1.y, d1);
      d2 = fdot2u(q1.z, p1.z, d2); d3 = fdot2u(q1.w, p1.w, d3);
      d0 = fdot2u(q2.x, p2.x, d0); d1 = fdot2u(q2.y, p2.y, d1);
      d2 = fdot2u(q2.z, p2.z, d2); d3 = fdot2u(q2.w, p2.w, d3);
      d0 = fdot2u(q3.x, p3.x, d0); d1 = fdot2u(q3.y, p3.y, d1);
      d2 = fdot2u(q3.z, p3.z, d2); d3 = fdot2u(q3.w, p3.w, d3);

      float sc = ((d0 + d1) + (d2 + d3)) * SCALE2;
      float w = exp2f(sc);
      l += w;
      __half2 w2 = uh2(pkh(w, w));
      oa[0]  = __hfma2(w2, uh2(v0.x), oa[0]);
      oa[1]  = __hfma2(w2, uh2(v0.y), oa[1]);
      oa[2]  = __hfma2(w2, uh2(v0.z), oa[2]);
      oa[3]  = __hfma2(w2, uh2(v0.w), oa[3]);
      oa[4]  = __hfma2(w2, uh2(v1.x), oa[4]);
      oa[5]  = __hfma2(w2, uh2(v1.y), oa[5]);
      oa[6]  = __hfma2(w2, uh2(v1.z), oa[6]);
      oa[7]  = __hfma2(w2, uh2(v1.w), oa[7]);
      oa[8]  = __hfma2(w2, uh2(v2.x), oa[8]);
      oa[9]  = __hfma2(w2, uh2(v2.y), oa[9]);
      oa[10] = __hfma2(w2, uh2(v2.z), oa[10]);
      oa[11] = __hfma2(w2, uh2(v2.w), oa[11]);
      oa[12] = __hfma2(w2, uh2(v3.x), oa[12]);
      oa[13] = __hfma2(w2, uh2(v3.y), oa[13]);
      oa[14] = __hfma2(w2, uh2(v3.z), oa[14]);
      oa[15] = __hfma2(w2, uh2(v3.w), oa[15]);
    }
  }

  float inv = 1.f / l;
  unsigned ow[8];
#pragma unroll
  for (int j = 0; j < 8; ++j) {
    float a0 = __low2float(oa[2 * j]) * inv;
    float a1 = __high2float(oa[2 * j]) * inv;
    float a2 = __low2float(oa[2 * j + 1]) * inv;
    float a3 = __high2float(oa[2 * j + 1]) * inv;
    (void)a2; (void)a3;
    ow[j] = 0;  // placeholder, filled below
    // pack pairs: [a1|a0] and next word [a3|a2] handled in store loop
  }
  // direct pack + store: 16 bf16 pairs -> 8 u32 -> 2 uint4
  uint4 s0, s1;
  s0.x = cvtpk(__low2float(oa[0]) * inv, __high2float(oa[0]) * inv);
  s0.y = cvtpk(__low2float(oa[1]) * inv, __high2float(oa[1]) * inv);
  s0.z = cvtpk(__low2float(oa[2]) * inv, __high2float(oa[2]) * inv);
  s0.w = cvtpk(__low2float(oa[3]) * inv, __high2float(oa[3]) * inv);
  s1.x = cvtpk(__low2float(oa[4]) * inv, __high2float(oa[4]) * inv);
  s1.y = cvtpk(__low2float(oa[5]) * inv, __high2float(oa[5]) * inv);
  s1.z = cvtpk(__low2float(oa[6]) * inv, __high2float(oa[6]) * inv);
  s1.w = cvtpk(__low2float(oa[7]) * inv, __high2float(oa[7]) * inv);
  *reinterpret_cast<uint4*>(ACC + pbase) = s0;
  *reinterpret_cast<uint4*>(ACC + pbase + 8) = s1;
  uint4 s2, s3;
  s2.x = cvtpk(__low2float(oa[8]) * inv, __high2float(oa[8]) * inv);
  s2.y = cvtpk(__low2float(oa[9]) * inv, __high2float(oa[9]) * inv);
  s2.z = cvtpk(__low2float(oa[10]) * inv, __high2float(oa[10]) * inv);
  s2.w = cvtpk(__low2float(oa[11]) * inv, __high2float(oa[11]) * inv);
  s3.x = cvtpk(__low2float(oa[12]) * inv, __high2float(oa[12]) * inv);
  s3.y = cvtpk(__low2float(oa[13]) * inv, __high2float(oa[13]) * inv);
  s3.z = cvtpk(__low2float(oa[14]) * inv, __high2float(oa[14]) * inv);
  s3.w = cvtpk(__low2float(oa[15]) * inv, __high2float(oa[15]) * inv);
  *reinterpret_cast<uint4*>(ACC + pbase + 16) = s2;
  *reinterpret_cast<uint4*>(ACC + pbase + 24) = s3;
}

// ---------------- output projection: 256x256 tile, swapped operands, float4 stores ----------------
__launch_bounds__(512, 2)
__global__ void out_gemm(const short* __restrict__ A, const short* __restrict__ WoT,
                         float* __restrict__ out) {
  __shared__ short As[2][256 * 64];
  __shared__ short Bs[2][256 * 64];
  const int t = threadIdx.x;
  const int bi = blockIdx.x;
  const int xcd = bi & 7;
  const int mt = xcd * 64 + (bi >> 3);
  const int m0 = mt * 256;
  const int wave = t >> 6, lane = t & 63;
  const int wm = (wave >> 2) * 128, wn = (wave & 3) * 64;
  const int lr = lane & 15, g = lane >> 4;

  const int ro = lane >> 3;
  const int colb = ((lane & 7) * 16) ^ (ro << 4);
  const char* aSrc0 = reinterpret_cast<const char*>(A + (size_t)(m0 + ro) * 256) + colb;
  const char* bSrc0 = reinterpret_cast<const char*>(WoT + (size_t)ro * 256) + colb;

  auto stage = [&](int buf, int ks) {
#pragma unroll
    for (int c = 0; c < 4; ++c) {
      int cc = wave * 4 + c;
      gld16(aSrc0 + (size_t)cc * 8 * 512 + ks * 128, (char*)As[buf] + cc * 1024);
      gld16(bSrc0 + (size_t)cc * 8 * 512 + ks * 128, (char*)Bs[buf] + cc * 1024);
    }
  };

  v4f acc[8][4];
#pragma unroll
  for (int i = 0; i < 8; ++i)
#pragma unroll
    for (int jj = 0; jj < 4; ++jj) acc[i][jj] = (v4f){0.f, 0.f, 0.f, 0.f};

  stage(0, 0);
  __syncthreads();

#pragma unroll 1
  for (int s = 0; s < 4; ++s) {
    const int buf = s & 1;
    if (s < 3) stage(buf ^ 1, s + 1);

    const char* aB = (const char*)As[buf];
    const char* bB = (const char*)Bs[buf];
#pragma unroll
    for (int kk = 0; kk < 2; ++kk) {
      v8s bfr[4];
#pragma unroll
      for (int jj = 0; jj < 4; ++jj) {
        int rn = wn + jj * 16 + lr;
        bfr[jj] = *reinterpret_cast<const v8s*>(
            bB + ((rn * 128 + kk * 64 + g * 16) ^ ((rn & 7) << 4)));
      }
#pragma unroll
      for (int i = 0; i < 8; ++i) {
        int row = wm + i * 16 + lr;
        v8s af = *reinterpret_cast<const v8s*>(
            aB + ((row * 128 + kk * 64 + g * 16) ^ ((row & 7) << 4)));
#pragma unroll
        for (int jj = 0; jj < 4; ++jj)
          acc[i][jj] = __builtin_amdgcn_mfma_f32_16x16x32_bf16(bfr[jj], af, acc[i][jj], 0, 0, 0);
      }
    }
    __syncthreads();
  }

#pragma unroll
  for (int i = 0; i < 8; ++i) {
    int p = m0 + wm + i * 16 + lr;
#pragma unroll
    for (int jj = 0; jj < 4; ++jj) {
      int nb = wn + jj * 16 + g * 4;
      float4 o;
      o.x = acc[i][jj][0]; o.y = acc[i][jj][1];
      o.z = acc[i][jj][2]; o.w = acc[i][jj][3];
      *reinterpret_cast<float4*>(out + (size_t)p * 256 + nb) = o;
    }
  }
}

extern "C" void kernel_launch(void* const* d_in, const int* in_sizes, int n_in,
                              void* d_out, int out_size, void* d_ws, size_t ws_size,
                              hipStream_t stream) {
  const float* x       = (const float*)d_in[0];
  const float* Wq      = (const float*)d_in[1];
  const float* Wk      = (const float*)d_in[2];
  const float* Wv      = (const float*)d_in[3];
  const float* Wout    = (const float*)d_in[4];
  const float* pos_emb = (const float*)d_in[5];
  float* out = (float*)d_out;

  char* ws = (char*)d_ws;
  short* WcT  = (short*)ws;                       // 768*256*2   = 393216 B
  short* WoT  = (short*)(ws + 393216);            // 256*256*2   = 131072 B
  short* Qb   = (short*)(ws + 524288);            // 131072*256*2 each
  short* Kb   = Qb + (size_t)131072 * 256;
  short* Vb   = Kb + (size_t)131072 * 256;
  short* ACCb = Vb + (size_t)131072 * 256;
  short* xb   = ACCb;   // alias: xb used only before attn writes ACCb

  prep_weights<<<768, 256, 0, stream>>>(Wq, Wk, Wv, Wout, WcT, WoT);
  x_cast<<<4096, 256, 0, stream>>>(x, xb);
  proj_gemm<<<1536, 512, 0, stream>>>(xb, WcT, pos_emb, Qb, Kb, Vb);
  attn_kernel<<<4096, 256, 0, stream>>>(Qb, Kb, Vb, pos_emb, ACCb);
  out_gemm<<<512, 512, 0, stream>>>(ACCb, WoT, out);
}

// Round 19
// 355.884 us; speedup vs baseline: 1.6279x; 1.6279x over previous
//
#include <hip/hip_runtime.h>
#include <hip/hip_fp16.h>

#define DEVI __device__ __forceinline__

typedef short v8s __attribute__((ext_vector_type(8)));
typedef float v4f __attribute__((ext_vector_type(4)));
typedef _Float16 h2v __attribute__((ext_vector_type(2)));
typedef __fp16 fp16x2 __attribute__((ext_vector_type(2)));
typedef unsigned short u16;

typedef __attribute__((address_space(3))) unsigned int lds_u32;
typedef const __attribute__((address_space(1))) unsigned int glb_u32;

DEVI float bf2f(short s) {
  union { unsigned u; float f; } cv;
  cv.u = ((unsigned)(u16)s) << 16;
  return cv.f;
}
DEVI short f2bf(float f) {
  union { float f; unsigned u; } cv; cv.f = f;
  unsigned u = cv.u;
  return (short)((u + 0x7FFFu + ((u >> 16) & 1u)) >> 16);
}
DEVI unsigned cvtpk(float lo, float hi) {  // packed bf16 [hi|lo], RNE (proven R14)
  unsigned r;
  asm("v_cvt_pk_bf16_f32 %0, %1, %2" : "=v"(r) : "v"(lo), "v"(hi));
  return r;
}
DEVI unsigned pkh(float a, float b) {      // packed f16 [b|a], RTZ
  union { fp16x2 h; unsigned u; } cv;
  cv.h = __builtin_amdgcn_cvt_pkrtz(a, b);
  return cv.u;
}
DEVI float fdot2u(unsigned a, unsigned b, float c) {  // f16 dot2, f32 accum (proven R17)
  union { unsigned u; h2v h; } ca, cb; ca.u = a; cb.u = b;
  return __builtin_amdgcn_fdot2(ca.h, cb.h, c, false);
}
DEVI float h2lo(unsigned u) { union { unsigned u; h2v h; } c; c.u = u; return (float)c.h.x; }
DEVI float h2hi(unsigned u) { union { unsigned u; h2v h; } c; c.u = u; return (float)c.h.y; }
DEVI __half2 uh2(unsigned u) { union { unsigned u; __half2 h; } c; c.u = u; return c.h; }
DEVI void gld16(const void* g, void* l) {
  __builtin_amdgcn_global_load_lds((glb_u32*)g, (lds_u32*)l, 16, 0, 0);
}

// ---------------- prep: transpose + cast weights to bf16 ----------------
__global__ void prep_weights(const float* __restrict__ Wq, const float* __restrict__ Wk,
                             const float* __restrict__ Wv, const float* __restrict__ Wout,
                             short* __restrict__ WcT, short* __restrict__ WoT) {
  int n = blockIdx.x;
  int k = threadIdx.x;
  float v;
  if (n < 256)      v = Wq[k * 256 + n];
  else if (n < 512) v = Wk[k * 256 + (n - 256)];
  else              v = Wv[k * 256 + (n - 512)];
  WcT[n * 256 + k] = f2bf(v);
  if (n < 256) WoT[n * 256 + k] = f2bf(Wout[k * 256 + n]);
}

// ---------------- x -> bf16 cast ----------------
__global__ void x_cast(const float* __restrict__ x, short* __restrict__ xb) {
  for (size_t gidx = (size_t)blockIdx.x * 256 + threadIdx.x; gidx < 4194304;
       gidx += (size_t)4096 * 256) {
    const float4* src = reinterpret_cast<const float4*>(x + gidx * 8);
    float4 a = src[0], c = src[1];
    v8s pk;
    pk[0] = f2bf(a.x); pk[1] = f2bf(a.y); pk[2] = f2bf(a.z); pk[3] = f2bf(a.w);
    pk[4] = f2bf(c.x); pk[5] = f2bf(c.y); pk[6] = f2bf(c.z); pk[7] = f2bf(c.w);
    *reinterpret_cast<v8s*>(xb + gidx * 8) = pk;
  }
}

// ---------------- QKV projection: 256x256 tile, swapped-operand MFMA, wide stores ----------------
// Q/K/V all emitted as packed f16 (attn consumes via fdot2 / hfma2).
__launch_bounds__(512, 2)
__global__ void proj_gemm(const short* __restrict__ xb, const short* __restrict__ WcT,
                          const float* __restrict__ pos_emb,
                          short* __restrict__ Qb, short* __restrict__ Kb,
                          short* __restrict__ Vb) {
  __shared__ short As[2][256 * 64];
  __shared__ short Bs[2][256 * 64];
  const int t = threadIdx.x;
  const int bi = blockIdx.x;
  const int xcd = bi & 7;
  const int j = bi >> 3;               // 0..191
  const int mtl = j / 3, nt = j % 3;
  const int mt = xcd * 64 + mtl;       // 0..511, bijective
  const int m0 = mt * 256, n0 = nt * 256;
  const int wave = t >> 6, lane = t & 63;
  const int wm = (wave >> 2) * 128, wn = (wave & 3) * 64;
  const int lr = lane & 15, g = lane >> 4;

  const int ro = lane >> 3;
  const int colb = ((lane & 7) * 16) ^ (ro << 4);
  const char* aSrc0 = reinterpret_cast<const char*>(xb + (size_t)(m0 + ro) * 256) + colb;
  const char* bSrc0 = reinterpret_cast<const char*>(WcT + (size_t)(n0 + ro) * 256) + colb;

  auto stage = [&](int buf, int ks) {
#pragma unroll
    for (int c = 0; c < 4; ++c) {
      int cc = wave * 4 + c;
      gld16(aSrc0 + (size_t)cc * 8 * 512 + ks * 128, (char*)As[buf] + cc * 1024);
      gld16(bSrc0 + (size_t)cc * 8 * 512 + ks * 128, (char*)Bs[buf] + cc * 1024);
    }
  };

  v4f acc[8][4];
#pragma unroll
  for (int i = 0; i < 8; ++i)
#pragma unroll
    for (int jj = 0; jj < 4; ++jj) acc[i][jj] = (v4f){0.f, 0.f, 0.f, 0.f};

  stage(0, 0);
  __syncthreads();

#pragma unroll 1
  for (int s = 0; s < 4; ++s) {
    const int buf = s & 1;
    if (s < 3) stage(buf ^ 1, s + 1);

    const char* aB = (const char*)As[buf];
    const char* bB = (const char*)Bs[buf];
#pragma unroll
    for (int kk = 0; kk < 2; ++kk) {
      v8s bfr[4];
#pragma unroll
      for (int jj = 0; jj < 4; ++jj) {
        int rn = wn + jj * 16 + lr;
        bfr[jj] = *reinterpret_cast<const v8s*>(
            bB + ((rn * 128 + kk * 64 + g * 16) ^ ((rn & 7) << 4)));
      }
#pragma unroll
      for (int i = 0; i < 8; ++i) {
        int row = wm + i * 16 + lr;
        v8s af = *reinterpret_cast<const v8s*>(
            aB + ((row * 128 + kk * 64 + g * 16) ^ ((row & 7) << 4)));
#pragma unroll
        for (int jj = 0; jj < 4; ++jj)
          acc[i][jj] = __builtin_amdgcn_mfma_f32_16x16x32_bf16(bfr[jj], af, acc[i][jj], 0, 0, 0);
      }
    }
    __syncthreads();
  }

  short* dst = (nt == 0) ? Qb : (nt == 1) ? Kb : Vb;
#pragma unroll
  for (int i = 0; i < 8; ++i) {
    int p = m0 + wm + i * 16 + lr;
    int qi = 0;
    if (nt == 0) {
      int yy = (p >> 7) & 127, xx = p & 127;
      qi = (yy - min(max(yy, 2), 125) + 2) * 5 + (xx - min(max(xx, 2), 125) + 2);
    }
#pragma unroll
    for (int jj = 0; jj < 4; ++jj) {
      int nb = wn + jj * 16 + g * 4;
      v4f a = acc[i][jj];
      if (nt == 0) {
        float4 pe4 = *reinterpret_cast<const float4*>(pos_emb + qi * 256 + nb);
        a[0] += pe4.x; a[1] += pe4.y; a[2] += pe4.z; a[3] += pe4.w;
      }
      uint2 pk;
      pk.x = pkh(a[0], a[1]);
      pk.y = pkh(a[2], a[3]);
      *reinterpret_cast<uint2*>(dst + (size_t)p * 256 + nb) = pk;
    }
  }
}

// ---------------- attention: split-F (R17 structure), f16 QK fdot2, f16 V hfma2 ----------------
__launch_bounds__(256, 4)
__global__ void attn_kernel(const short* __restrict__ Qb, const short* __restrict__ Kb,
                            const short* __restrict__ Vb, const float* __restrict__ pos_emb,
                            short* __restrict__ ACC) {
  __shared__ float pe[25 * 256];
  for (int i = threadIdx.x; i < 1600; i += 256) {
    float4 vv = reinterpret_cast<const float4*>(pos_emb)[i];
    int w = i * 4;
    int f = w & 255;
    int dst = (w & ~255) + (f ^ ((f >> 5) << 2));
    *reinterpret_cast<float4*>(pe + dst) = vv;
  }

  const int t = threadIdx.x;
  const int half = t & 1, h = (t >> 1) & 7, pl = t >> 4;
  const int id = blockIdx.x;
  const int b = id & 7;
  const int local = id >> 3;
  const int bx = local & 31, by = local >> 5;
  const int xx = bx * 4 + (pl & 3);
  const int yy = by * 4 + (pl >> 2);
  const int yc = min(max(yy, 2), 125), xc = min(max(xx, 2), 125);
  const int fo = h * 32 + half * 16;
  const int hx4 = h << 2;
  const size_t pbase = ((size_t)((b * 128 + yy) * 128 + xx)) * 256 + fo;
  const size_t cbase = ((size_t)((b * 128 + yc) * 128 + xc)) * 256 + fo;
  const float SCALE2 = 0.17677669529663689f * 1.4426950408889634f;  // rsqrt(32)*log2(e)

  // Q slice: packed f16 (for fdot2) + unpacked f32 (for pe-dot path)
  uint4 qA = *reinterpret_cast<const uint4*>(Qb + pbase);
  uint4 qB = *reinterpret_cast<const uint4*>(Qb + pbase + 8);
  float q[16];
  q[0] = h2lo(qA.x); q[1] = h2hi(qA.x); q[2] = h2lo(qA.y); q[3] = h2hi(qA.y);
  q[4] = h2lo(qA.z); q[5] = h2hi(qA.z); q[6] = h2lo(qA.w); q[7] = h2hi(qA.w);
  q[8] = h2lo(qB.x); q[9] = h2hi(qB.x); q[10] = h2lo(qB.y); q[11] = h2hi(qB.y);
  q[12] = h2lo(qB.z); q[13] = h2hi(qB.z); q[14] = h2lo(qB.w); q[15] = h2hi(qB.w);
  __syncthreads();

  float l = 0.f;
  __half2 oa[8];
#pragma unroll
  for (int jv = 0; jv < 8; ++jv) oa[jv] = uh2(0u);

  const short* kb = Kb + cbase;
  const short* vb = Vb + cbase;
  const float* pb = pe + h * 32;
  const int j0 = (half * 16) ^ hx4;
  const int j1 = (half * 16 + 4) ^ hx4;
  const int j2 = (half * 16 + 8) ^ hx4;
  const int j3 = (half * 16 + 12) ^ hx4;

  uint4 kn0, kn1;
  uint4 vn0;
  {
    const short* kp = kb + (-2 * 128 - 2) * 256;
    const short* vp = vb + (-2 * 128 - 2) * 256;
    kn0 = *reinterpret_cast<const uint4*>(kp);
    kn1 = *reinterpret_cast<const uint4*>(kp + 8);
    vn0 = *reinterpret_cast<const uint4*>(vp);
  }

#pragma unroll 1
  for (int dy = -2; dy <= 2; ++dy) {
    const float* prow = pb + ((dy + 2) * 5) * 256;
#pragma unroll 1
    for (int dx = -2; dx <= 2; ++dx) {
      uint4 k0 = kn0, k1 = kn1;
      uint4 v0 = vn0;
      int ndx = dx + 1, ndy = dy;
      if (ndx > 2) { ndx = -2; ndy = dy + 1; }
      if (ndy <= 2) {
        const short* kp2 = kb + (ndy * 128 + ndx) * 256;
        const short* vp2 = vb + (ndy * 128 + ndx) * 256;
        kn0 = *reinterpret_cast<const uint4*>(kp2);
        kn1 = *reinterpret_cast<const uint4*>(kp2 + 8);
        vn0 = *reinterpret_cast<const uint4*>(vp2);
      }
      const float* pp = prow + (dx + 2) * 256;
      float4 p0 = *reinterpret_cast<const float4*>(pp + j0);
      float4 p1 = *reinterpret_cast<const float4*>(pp + j1);
      float4 p2 = *reinterpret_cast<const float4*>(pp + j2);
      float4 p3 = *reinterpret_cast<const float4*>(pp + j3);

      // QK dot: 8 packed f16 dot2 (f32 accumulate)
      float d0 = 0.f, d1 = 0.f, d2 = 0.f, d3 = 0.f;
      d0 = fdot2u(qA.x, k0.x, d0); d1 = fdot2u(qA.y, k0.y, d1);
      d2 = fdot2u(qA.z, k0.z, d2); d3 = fdot2u(qA.w, k0.w, d3);
      d0 = fdot2u(qB.x, k1.x, d0); d1 = fdot2u(qB.y, k1.y, d1);
      d2 = fdot2u(qB.z, k1.z, d2); d3 = fdot2u(qB.w, k1.w, d3);

      // pe contribution: f32 fma path (R14/R17 verbatim)
      d0 = fmaf(q[0], p0.x, d0); d0 = fmaf(q[1], p0.y, d0);
      d0 = fmaf(q[2], p0.z, d0); d0 = fmaf(q[3], p0.w, d0);
      d1 = fmaf(q[4], p1.x, d1); d1 = fmaf(q[5], p1.y, d1);
      d1 = fmaf(q[6], p1.z, d1); d1 = fmaf(q[7], p1.w, d1);
      d2 = fmaf(q[8], p2.x, d2); d2 = fmaf(q[9], p2.y, d2);
      d2 = fmaf(q[10], p2.z, d2); d2 = fmaf(q[11], p2.w, d2);
      d3 = fmaf(q[12], p3.x, d3); d3 = fmaf(q[13], p3.y, d3);
      d3 = fmaf(q[14], p3.z, d3); d3 = fmaf(q[15], p3.w, d3);

      float part = ((d0 + d1) + (d2 + d3)) * SCALE2;
      float full = part + __shfl_xor(part, 1);
      float w = exp2f(full);
      l += w;
      // V accumulate: 8 packed f16 fma (R18-validated numerics)
      __half2 w2 = uh2(pkh(w, w));
      oa[0] = __hfma2(w2, uh2(v0.x), oa[0]);
      oa[1] = __hfma2(w2, uh2(v0.y), oa[1]);
      oa[2] = __hfma2(w2, uh2(v0.z), oa[2]);
      oa[3] = __hfma2(w2, uh2(v0.w), oa[3]);
      uint4 v1 = *reinterpret_cast<const uint4*>(vb + (dy * 128 + dx) * 256 + 8);
      oa[4] = __hfma2(w2, uh2(v1.x), oa[4]);
      oa[5] = __hfma2(w2, uh2(v1.y), oa[5]);
      oa[6] = __hfma2(w2, uh2(v1.z), oa[6]);
      oa[7] = __hfma2(w2, uh2(v1.w), oa[7]);
    }
  }

  float inv = 1.f / l;
  uint4 s0, s1;
  s0.x = cvtpk(__low2float(oa[0]) * inv, __high2float(oa[0]) * inv);
  s0.y = cvtpk(__low2float(oa[1]) * inv, __high2float(oa[1]) * inv);
  s0.z = cvtpk(__low2float(oa[2]) * inv, __high2float(oa[2]) * inv);
  s0.w = cvtpk(__low2float(oa[3]) * inv, __high2float(oa[3]) * inv);
  s1.x = cvtpk(__low2float(oa[4]) * inv, __high2float(oa[4]) * inv);
  s1.y = cvtpk(__low2float(oa[5]) * inv, __high2float(oa[5]) * inv);
  s1.z = cvtpk(__low2float(oa[6]) * inv, __high2float(oa[6]) * inv);
  s1.w = cvtpk(__low2float(oa[7]) * inv, __high2float(oa[7]) * inv);
  *reinterpret_cast<uint4*>(ACC + pbase) = s0;
  *reinterpret_cast<uint4*>(ACC + pbase + 8) = s1;
}

// ---------------- output projection: 256x256 tile, swapped operands, float4 stores ----------------
__launch_bounds__(512, 2)
__global__ void out_gemm(const short* __restrict__ A, const short* __restrict__ WoT,
                         float* __restrict__ out) {
  __shared__ short As[2][256 * 64];
  __shared__ short Bs[2][256 * 64];
  const int t = threadIdx.x;
  const int bi = blockIdx.x;
  const int xcd = bi & 7;
  const int mt = xcd * 64 + (bi >> 3);
  const int m0 = mt * 256;
  const int wave = t >> 6, lane = t & 63;
  const int wm = (wave >> 2) * 128, wn = (wave & 3) * 64;
  const int lr = lane & 15, g = lane >> 4;

  const int ro = lane >> 3;
  const int colb = ((lane & 7) * 16) ^ (ro << 4);
  const char* aSrc0 = reinterpret_cast<const char*>(A + (size_t)(m0 + ro) * 256) + colb;
  const char* bSrc0 = reinterpret_cast<const char*>(WoT + (size_t)ro * 256) + colb;

  auto stage = [&](int buf, int ks) {
#pragma unroll
    for (int c = 0; c < 4; ++c) {
      int cc = wave * 4 + c;
      gld16(aSrc0 + (size_t)cc * 8 * 512 + ks * 128, (char*)As[buf] + cc * 1024);
      gld16(bSrc0 + (size_t)cc * 8 * 512 + ks * 128, (char*)Bs[buf] + cc * 1024);
    }
  };

  v4f acc[8][4];
#pragma unroll
  for (int i = 0; i < 8; ++i)
#pragma unroll
    for (int jj = 0; jj < 4; ++jj) acc[i][jj] = (v4f){0.f, 0.f, 0.f, 0.f};

  stage(0, 0);
  __syncthreads();

#pragma unroll 1
  for (int s = 0; s < 4; ++s) {
    const int buf = s & 1;
    if (s < 3) stage(buf ^ 1, s + 1);

    const char* aB = (const char*)As[buf];
    const char* bB = (const char*)Bs[buf];
#pragma unroll
    for (int kk = 0; kk < 2; ++kk) {
      v8s bfr[4];
#pragma unroll
      for (int jj = 0; jj < 4; ++jj) {
        int rn = wn + jj * 16 + lr;
        bfr[jj] = *reinterpret_cast<const v8s*>(
            bB + ((rn * 128 + kk * 64 + g * 16) ^ ((rn & 7) << 4)));
      }
#pragma unroll
      for (int i = 0; i < 8; ++i) {
        int row = wm + i * 16 + lr;
        v8s af = *reinterpret_cast<const v8s*>(
            aB + ((row * 128 + kk * 64 + g * 16) ^ ((row & 7) << 4)));
#pragma unroll
        for (int jj = 0; jj < 4; ++jj)
          acc[i][jj] = __builtin_amdgcn_mfma_f32_16x16x32_bf16(bfr[jj], af, acc[i][jj], 0, 0, 0);
      }
    }
    __syncthreads();
  }

#pragma unroll
  for (int i = 0; i < 8; ++i) {
    int p = m0 + wm + i * 16 + lr;
#pragma unroll
    for (int jj = 0; jj < 4; ++jj) {
      int nb = wn + jj * 16 + g * 4;
      float4 o;
      o.x = acc[i][jj][0]; o.y = acc[i][jj][1];
      o.z = acc[i][jj][2]; o.w = acc[i][jj][3];
      *reinterpret_cast<float4*>(out + (size_t)p * 256 + nb) = o;
    }
  }
}

extern "C" void kernel_launch(void* const* d_in, const int* in_sizes, int n_in,
                              void* d_out, int out_size, void* d_ws, size_t ws_size,
                              hipStream_t stream) {
  const float* x       = (const float*)d_in[0];
  const float* Wq      = (const float*)d_in[1];
  const float* Wk      = (const float*)d_in[2];
  const float* Wv      = (const float*)d_in[3];
  const float* Wout    = (const float*)d_in[4];
  const float* pos_emb = (const float*)d_in[5];
  float* out = (float*)d_out;

  char* ws = (char*)d_ws;
  short* WcT  = (short*)ws;                       // 768*256*2   = 393216 B
  short* WoT  = (short*)(ws + 393216);            // 256*256*2   = 131072 B
  short* Qb   = (short*)(ws + 524288);            // 131072*256*2 each
  short* Kb   = Qb + (size_t)131072 * 256;
  short* Vb   = Kb + (size_t)131072 * 256;
  short* ACCb = Vb + (size_t)131072 * 256;
  short* xb   = ACCb;   // alias: xb used only before attn writes ACCb

  prep_weights<<<768, 256, 0, stream>>>(Wq, Wk, Wv, Wout, WcT, WoT);
  x_cast<<<4096, 256, 0, stream>>>(x, xb);
  proj_gemm<<<1536, 512, 0, stream>>>(xb, WcT, pos_emb, Qb, Kb, Vb);
  attn_kernel<<<8192, 256, 0, stream>>>(Qb, Kb, Vb, pos_emb, ACCb);
  out_gemm<<<512, 512, 0, stream>>>(ACCb, WoT, out);
}

// Round 20
// 348.042 us; speedup vs baseline: 1.6646x; 1.0225x over previous
//
#include <hip/hip_runtime.h>
#include <hip/hip_fp16.h>

#define DEVI __device__ __forceinline__

typedef short v8s __attribute__((ext_vector_type(8)));
typedef float v4f __attribute__((ext_vector_type(4)));
typedef _Float16 h2v __attribute__((ext_vector_type(2)));
typedef __fp16 fp16x2 __attribute__((ext_vector_type(2)));
typedef unsigned short u16;

typedef __attribute__((address_space(3))) unsigned int lds_u32;
typedef const __attribute__((address_space(1))) unsigned int glb_u32;

DEVI float bf2f(short s) {
  union { unsigned u; float f; } cv;
  cv.u = ((unsigned)(u16)s) << 16;
  return cv.f;
}
DEVI short f2bf(float f) {
  union { float f; unsigned u; } cv; cv.f = f;
  unsigned u = cv.u;
  return (short)((u + 0x7FFFu + ((u >> 16) & 1u)) >> 16);
}
DEVI unsigned cvtpk(float lo, float hi) {  // packed bf16 [hi|lo], RNE (proven R14)
  unsigned r;
  asm("v_cvt_pk_bf16_f32 %0, %1, %2" : "=v"(r) : "v"(lo), "v"(hi));
  return r;
}
DEVI unsigned pkh(float a, float b) {      // packed f16 [b|a], RTZ
  union { fp16x2 h; unsigned u; } cv;
  cv.h = __builtin_amdgcn_cvt_pkrtz(a, b);
  return cv.u;
}
DEVI float fdot2u(unsigned a, unsigned b, float c) {  // f16 dot2, f32 accum (proven R17)
  union { unsigned u; h2v h; } ca, cb; ca.u = a; cb.u = b;
  return __builtin_amdgcn_fdot2(ca.h, cb.h, c, false);
}
DEVI __half2 uh2(unsigned u) { union { unsigned u; __half2 h; } c; c.u = u; return c.h; }
DEVI void gld16(const void* g, void* l) {
  __builtin_amdgcn_global_load_lds((glb_u32*)g, (lds_u32*)l, 16, 0, 0);
}

// ---------------- prep: transpose + cast weights to bf16 ----------------
__global__ void prep_weights(const float* __restrict__ Wq, const float* __restrict__ Wk,
                             const float* __restrict__ Wv, const float* __restrict__ Wout,
                             short* __restrict__ WcT, short* __restrict__ WoT) {
  int n = blockIdx.x;
  int k = threadIdx.x;
  float v;
  if (n < 256)      v = Wq[k * 256 + n];
  else if (n < 512) v = Wk[k * 256 + (n - 256)];
  else              v = Wv[k * 256 + (n - 512)];
  WcT[n * 256 + k] = f2bf(v);
  if (n < 256) WoT[n * 256 + k] = f2bf(Wout[k * 256 + n]);
}

// ---------------- x -> bf16 cast ----------------
__global__ void x_cast(const float* __restrict__ x, short* __restrict__ xb) {
  for (size_t gidx = (size_t)blockIdx.x * 256 + threadIdx.x; gidx < 4194304;
       gidx += (size_t)4096 * 256) {
    const float4* src = reinterpret_cast<const float4*>(x + gidx * 8);
    float4 a = src[0], c = src[1];
    v8s pk;
    pk[0] = f2bf(a.x); pk[1] = f2bf(a.y); pk[2] = f2bf(a.z); pk[3] = f2bf(a.w);
    pk[4] = f2bf(c.x); pk[5] = f2bf(c.y); pk[6] = f2bf(c.z); pk[7] = f2bf(c.w);
    *reinterpret_cast<v8s*>(xb + gidx * 8) = pk;
  }
}

// ---------------- QKV projection: 256x256 tile, swapped-operand MFMA, wide stores ----------------
// Q/K/V all emitted as packed f16 (attn consumes via fdot2 / hfma2).
__launch_bounds__(512, 2)
__global__ void proj_gemm(const short* __restrict__ xb, const short* __restrict__ WcT,
                          const float* __restrict__ pos_emb,
                          short* __restrict__ Qb, short* __restrict__ Kb,
                          short* __restrict__ Vb) {
  __shared__ short As[2][256 * 64];
  __shared__ short Bs[2][256 * 64];
  const int t = threadIdx.x;
  const int bi = blockIdx.x;
  const int xcd = bi & 7;
  const int j = bi >> 3;               // 0..191
  const int mtl = j / 3, nt = j % 3;
  const int mt = xcd * 64 + mtl;       // 0..511, bijective
  const int m0 = mt * 256, n0 = nt * 256;
  const int wave = t >> 6, lane = t & 63;
  const int wm = (wave >> 2) * 128, wn = (wave & 3) * 64;
  const int lr = lane & 15, g = lane >> 4;

  const int ro = lane >> 3;
  const int colb = ((lane & 7) * 16) ^ (ro << 4);
  const char* aSrc0 = reinterpret_cast<const char*>(xb + (size_t)(m0 + ro) * 256) + colb;
  const char* bSrc0 = reinterpret_cast<const char*>(WcT + (size_t)(n0 + ro) * 256) + colb;

  auto stage = [&](int buf, int ks) {
#pragma unroll
    for (int c = 0; c < 4; ++c) {
      int cc = wave * 4 + c;
      gld16(aSrc0 + (size_t)cc * 8 * 512 + ks * 128, (char*)As[buf] + cc * 1024);
      gld16(bSrc0 + (size_t)cc * 8 * 512 + ks * 128, (char*)Bs[buf] + cc * 1024);
    }
  };

  v4f acc[8][4];
#pragma unroll
  for (int i = 0; i < 8; ++i)
#pragma unroll
    for (int jj = 0; jj < 4; ++jj) acc[i][jj] = (v4f){0.f, 0.f, 0.f, 0.f};

  stage(0, 0);
  __syncthreads();

#pragma unroll 1
  for (int s = 0; s < 4; ++s) {
    const int buf = s & 1;
    if (s < 3) stage(buf ^ 1, s + 1);

    const char* aB = (const char*)As[buf];
    const char* bB = (const char*)Bs[buf];
#pragma unroll
    for (int kk = 0; kk < 2; ++kk) {
      v8s bfr[4];
#pragma unroll
      for (int jj = 0; jj < 4; ++jj) {
        int rn = wn + jj * 16 + lr;
        bfr[jj] = *reinterpret_cast<const v8s*>(
            bB + ((rn * 128 + kk * 64 + g * 16) ^ ((rn & 7) << 4)));
      }
#pragma unroll
      for (int i = 0; i < 8; ++i) {
        int row = wm + i * 16 + lr;
        v8s af = *reinterpret_cast<const v8s*>(
            aB + ((row * 128 + kk * 64 + g * 16) ^ ((row & 7) << 4)));
#pragma unroll
        for (int jj = 0; jj < 4; ++jj)
          acc[i][jj] = __builtin_amdgcn_mfma_f32_16x16x32_bf16(bfr[jj], af, acc[i][jj], 0, 0, 0);
      }
    }
    __syncthreads();
  }

  short* dst = (nt == 0) ? Qb : (nt == 1) ? Kb : Vb;
#pragma unroll
  for (int i = 0; i < 8; ++i) {
    int p = m0 + wm + i * 16 + lr;
    int qi = 0;
    if (nt == 0) {
      int yy = (p >> 7) & 127, xx = p & 127;
      qi = (yy - min(max(yy, 2), 125) + 2) * 5 + (xx - min(max(xx, 2), 125) + 2);
    }
#pragma unroll
    for (int jj = 0; jj < 4; ++jj) {
      int nb = wn + jj * 16 + g * 4;
      v4f a = acc[i][jj];
      if (nt == 0) {
        float4 pe4 = *reinterpret_cast<const float4*>(pos_emb + qi * 256 + nb);
        a[0] += pe4.x; a[1] += pe4.y; a[2] += pe4.z; a[3] += pe4.w;
      }
      uint2 pk;
      pk.x = pkh(a[0], a[1]);
      pk.y = pkh(a[2], a[3]);
      *reinterpret_cast<uint2*>(dst + (size_t)p * 256 + nb) = pk;
    }
  }
}

// ---------------- attention: split-F, all-f16 datapath (QK+pe fdot2, V hfma2) ----------------
// pe packed-f16 in LDS (12.8 KB), swizzle w ^= ((w>>5)&3)<<1 -> 16 slices on 16 distinct banks.
__launch_bounds__(256, 4)
__global__ void attn_kernel(const short* __restrict__ Qb, const short* __restrict__ Kb,
                            const short* __restrict__ Vb, const float* __restrict__ pos_emb,
                            short* __restrict__ ACC) {
  __shared__ unsigned pe16[25 * 128];   // packed f16 pairs, word-swizzled
  for (int i = threadIdx.x; i < 1600; i += 256) {
    float4 vv = reinterpret_cast<const float4*>(pos_emb)[i];
    int s = i >> 6;
    int jw = (i & 63) * 2;                    // even word index in row
    int e = ((jw >> 5) & 3) << 1;
    uint2 pk2;
    pk2.x = pkh(vv.x, vv.y);
    pk2.y = pkh(vv.z, vv.w);
    *reinterpret_cast<uint2*>(pe16 + s * 128 + (jw ^ e)) = pk2;
  }

  const int t = threadIdx.x;
  const int half = t & 1, h = (t >> 1) & 7, pl = t >> 4;
  const int id = blockIdx.x;
  const int b = id & 7;
  const int local = id >> 3;
  const int bx = local & 31, by = local >> 5;
  const int xx = bx * 4 + (pl & 3);
  const int yy = by * 4 + (pl >> 2);
  const int yc = min(max(yy, 2), 125), xc = min(max(xx, 2), 125);
  const int fo = h * 32 + half * 16;
  const size_t pbase = ((size_t)((b * 128 + yy) * 128 + xx)) * 256 + fo;
  const size_t cbase = ((size_t)((b * 128 + yc) * 128 + xc)) * 256 + fo;
  const float SCALE2 = 0.17677669529663689f * 1.4426950408889634f;  // rsqrt(32)*log2(e)

  // Q slice: packed f16 only (pe path also packed now)
  uint4 qA = *reinterpret_cast<const uint4*>(Qb + pbase);
  uint4 qB = *reinterpret_cast<const uint4*>(Qb + pbase + 8);
  __syncthreads();

  float l = 0.f;
  __half2 oa[8];
#pragma unroll
  for (int jv = 0; jv < 8; ++jv) oa[jv] = uh2(0u);

  const short* kb = Kb + cbase;
  const short* vb = Vb + cbase;
  const int sw = h * 16 + half * 8;     // slice base word
  const int e = (h >> 1) << 1;          // ((sw>>5)&3)<<1

  uint4 kn0, kn1, vn0, vn1;
  {
    const short* kp = kb + (-2 * 128 - 2) * 256;
    const short* vp = vb + (-2 * 128 - 2) * 256;
    kn0 = *reinterpret_cast<const uint4*>(kp);
    kn1 = *reinterpret_cast<const uint4*>(kp + 8);
    vn0 = *reinterpret_cast<const uint4*>(vp);
    vn1 = *reinterpret_cast<const uint4*>(vp + 8);
  }

#pragma unroll 1
  for (int dy = -2; dy <= 2; ++dy) {
    const unsigned* prow = pe16 + ((dy + 2) * 5) * 128 + sw;
#pragma unroll 1
    for (int dx = -2; dx <= 2; ++dx) {
      uint4 k0 = kn0, k1 = kn1, v0 = vn0, v1 = vn1;
      int ndx = dx + 1, ndy = dy;
      if (ndx > 2) { ndx = -2; ndy = dy + 1; }
      if (ndy <= 2) {
        const short* kp2 = kb + (ndy * 128 + ndx) * 256;
        const short* vp2 = vb + (ndy * 128 + ndx) * 256;
        kn0 = *reinterpret_cast<const uint4*>(kp2);
        kn1 = *reinterpret_cast<const uint4*>(kp2 + 8);
        vn0 = *reinterpret_cast<const uint4*>(vp2);
        vn1 = *reinterpret_cast<const uint4*>(vp2 + 8);
      }
      const unsigned* ps = prow + (dx + 2) * 128;
      uint2 pp0 = *reinterpret_cast<const uint2*>(ps + (0 ^ e));
      uint2 pp1 = *reinterpret_cast<const uint2*>(ps + (2 ^ e));
      uint2 pp2 = *reinterpret_cast<const uint2*>(ps + (4 ^ e));
      uint2 pp3 = *reinterpret_cast<const uint2*>(ps + (6 ^ e));

      // QK dot + pe dot: 16 packed f16 dot2 (f32 accumulate)
      float d0 = 0.f, d1 = 0.f, d2 = 0.f, d3 = 0.f;
      d0 = fdot2u(qA.x, k0.x, d0); d1 = fdot2u(qA.y, k0.y, d1);
      d2 = fdot2u(qA.z, k0.z, d2); d3 = fdot2u(qA.w, k0.w, d3);
      d0 = fdot2u(qB.x, k1.x, d0); d1 = fdot2u(qB.y, k1.y, d1);
      d2 = fdot2u(qB.z, k1.z, d2); d3 = fdot2u(qB.w, k1.w, d3);
      d0 = fdot2u(qA.x, pp0.x, d0); d1 = fdot2u(qA.y, pp0.y, d1);
      d2 = fdot2u(qA.z, pp1.x, d2); d3 = fdot2u(qA.w, pp1.y, d3);
      d0 = fdot2u(qB.x, pp2.x, d0); d1 = fdot2u(qB.y, pp2.y, d1);
      d2 = fdot2u(qB.z, pp3.x, d2); d3 = fdot2u(qB.w, pp3.y, d3);

      float part = ((d0 + d1) + (d2 + d3)) * SCALE2;
      float full = part + __shfl_xor(part, 1);
      float w = exp2f(full);
      l += w;
      __half2 w2 = uh2(pkh(w, w));
      oa[0] = __hfma2(w2, uh2(v0.x), oa[0]);
      oa[1] = __hfma2(w2, uh2(v0.y), oa[1]);
      oa[2] = __hfma2(w2, uh2(v0.z), oa[2]);
      oa[3] = __hfma2(w2, uh2(v0.w), oa[3]);
      oa[4] = __hfma2(w2, uh2(v1.x), oa[4]);
      oa[5] = __hfma2(w2, uh2(v1.y), oa[5]);
      oa[6] = __hfma2(w2, uh2(v1.z), oa[6]);
      oa[7] = __hfma2(w2, uh2(v1.w), oa[7]);
    }
  }

  float inv = 1.f / l;
  uint4 s0, s1;
  s0.x = cvtpk(__low2float(oa[0]) * inv, __high2float(oa[0]) * inv);
  s0.y = cvtpk(__low2float(oa[1]) * inv, __high2float(oa[1]) * inv);
  s0.z = cvtpk(__low2float(oa[2]) * inv, __high2float(oa[2]) * inv);
  s0.w = cvtpk(__low2float(oa[3]) * inv, __high2float(oa[3]) * inv);
  s1.x = cvtpk(__low2float(oa[4]) * inv, __high2float(oa[4]) * inv);
  s1.y = cvtpk(__low2float(oa[5]) * inv, __high2float(oa[5]) * inv);
  s1.z = cvtpk(__low2float(oa[6]) * inv, __high2float(oa[6]) * inv);
  s1.w = cvtpk(__low2float(oa[7]) * inv, __high2float(oa[7]) * inv);
  *reinterpret_cast<uint4*>(ACC + pbase) = s0;
  *reinterpret_cast<uint4*>(ACC + pbase + 8) = s1;
}

// ---------------- output projection: 256x256 tile, swapped operands, float4 stores ----------------
__launch_bounds__(512, 2)
__global__ void out_gemm(const short* __restrict__ A, const short* __restrict__ WoT,
                         float* __restrict__ out) {
  __shared__ short As[2][256 * 64];
  __shared__ short Bs[2][256 * 64];
  const int t = threadIdx.x;
  const int bi = blockIdx.x;
  const int xcd = bi & 7;
  const int mt = xcd * 64 + (bi >> 3);
  const int m0 = mt * 256;
  const int wave = t >> 6, lane = t & 63;
  const int wm = (wave >> 2) * 128, wn = (wave & 3) * 64;
  const int lr = lane & 15, g = lane >> 4;

  const int ro = lane >> 3;
  const int colb = ((lane & 7) * 16) ^ (ro << 4);
  const char* aSrc0 = reinterpret_cast<const char*>(A + (size_t)(m0 + ro) * 256) + colb;
  const char* bSrc0 = reinterpret_cast<const char*>(WoT + (size_t)ro * 256) + colb;

  auto stage = [&](int buf, int ks) {
#pragma unroll
    for (int c = 0; c < 4; ++c) {
      int cc = wave * 4 + c;
      gld16(aSrc0 + (size_t)cc * 8 * 512 + ks * 128, (char*)As[buf] + cc * 1024);
      gld16(bSrc0 + (size_t)cc * 8 * 512 + ks * 128, (char*)Bs[buf] + cc * 1024);
    }
  };

  v4f acc[8][4];
#pragma unroll
  for (int i = 0; i < 8; ++i)
#pragma unroll
    for (int jj = 0; jj < 4; ++jj) acc[i][jj] = (v4f){0.f, 0.f, 0.f, 0.f};

  stage(0, 0);
  __syncthreads();

#pragma unroll 1
  for (int s = 0; s < 4; ++s) {
    const int buf = s & 1;
    if (s < 3) stage(buf ^ 1, s + 1);

    const char* aB = (const char*)As[buf];
    const char* bB = (const char*)Bs[buf];
#pragma unroll
    for (int kk = 0; kk < 2; ++kk) {
      v8s bfr[4];
#pragma unroll
      for (int jj = 0; jj < 4; ++jj) {
        int rn = wn + jj * 16 + lr;
        bfr[jj] = *reinterpret_cast<const v8s*>(
            bB + ((rn * 128 + kk * 64 + g * 16) ^ ((rn & 7) << 4)));
      }
#pragma unroll
      for (int i = 0; i < 8; ++i) {
        int row = wm + i * 16 + lr;
        v8s af = *reinterpret_cast<const v8s*>(
            aB + ((row * 128 + kk * 64 + g * 16) ^ ((row & 7) << 4)));
#pragma unroll
        for (int jj = 0; jj < 4; ++jj)
          acc[i][jj] = __builtin_amdgcn_mfma_f32_16x16x32_bf16(bfr[jj], af, acc[i][jj], 0, 0, 0);
      }
    }
    __syncthreads();
  }

#pragma unroll
  for (int i = 0; i < 8; ++i) {
    int p = m0 + wm + i * 16 + lr;
#pragma unroll
    for (int jj = 0; jj < 4; ++jj) {
      int nb = wn + jj * 16 + g * 4;
      float4 o;
      o.x = acc[i][jj][0]; o.y = acc[i][jj][1];
      o.z = acc[i][jj][2]; o.w = acc[i][jj][3];
      *reinterpret_cast<float4*>(out + (size_t)p * 256 + nb) = o;
    }
  }
}

extern "C" void kernel_launch(void* const* d_in, const int* in_sizes, int n_in,
                              void* d_out, int out_size, void* d_ws, size_t ws_size,
                              hipStream_t stream) {
  const float* x       = (const float*)d_in[0];
  const float* Wq      = (const float*)d_in[1];
  const float* Wk      = (const float*)d_in[2];
  const float* Wv      = (const float*)d_in[3];
  const float* Wout    = (const float*)d_in[4];
  const float* pos_emb = (const float*)d_in[5];
  float* out = (float*)d_out;

  char* ws = (char*)d_ws;
  short* WcT  = (short*)ws;                       // 768*256*2   = 393216 B
  short* WoT  = (short*)(ws + 393216);            // 256*256*2   = 131072 B
  short* Qb   = (short*)(ws + 524288);            // 131072*256*2 each
  short* Kb   = Qb + (size_t)131072 * 256;
  short* Vb   = Kb + (size_t)131072 * 256;
  short* ACCb = Vb + (size_t)131072 * 256;
  short* xb   = ACCb;   // alias: xb used only before attn writes ACCb

  prep_weights<<<768, 256, 0, stream>>>(Wq, Wk, Wv, Wout, WcT, WoT);
  x_cast<<<4096, 256, 0, stream>>>(x, xb);
  proj_gemm<<<1536, 512, 0, stream>>>(xb, WcT, pos_emb, Qb, Kb, Vb);
  attn_kernel<<<8192, 256, 0, stream>>>(Qb, Kb, Vb, pos_emb, ACCb);
  out_gemm<<<512, 512, 0, stream>>>(ACCb, WoT, out);
}

// Round 21
// 321.809 us; speedup vs baseline: 1.8003x; 1.0815x over previous
//
#include <hip/hip_runtime.h>
#include <hip/hip_fp16.h>

#define DEVI __device__ __forceinline__

typedef short v8s __attribute__((ext_vector_type(8)));
typedef float v4f __attribute__((ext_vector_type(4)));
typedef _Float16 h2v __attribute__((ext_vector_type(2)));
typedef __fp16 fp16x2 __attribute__((ext_vector_type(2)));
typedef unsigned short u16;

typedef __attribute__((address_space(3))) unsigned int lds_u32;
typedef const __attribute__((address_space(1))) unsigned int glb_u32;

DEVI float bf2f(short s) {
  union { unsigned u; float f; } cv;
  cv.u = ((unsigned)(u16)s) << 16;
  return cv.f;
}
DEVI short f2bf(float f) {
  union { float f; unsigned u; } cv; cv.f = f;
  unsigned u = cv.u;
  return (short)((u + 0x7FFFu + ((u >> 16) & 1u)) >> 16);
}
DEVI unsigned cvtpk(float lo, float hi) {  // packed bf16 [hi|lo], RNE (proven R14)
  unsigned r;
  asm("v_cvt_pk_bf16_f32 %0, %1, %2" : "=v"(r) : "v"(lo), "v"(hi));
  return r;
}
DEVI unsigned pkh(float a, float b) {      // packed f16 [b|a], RTZ
  union { fp16x2 h; unsigned u; } cv;
  cv.h = __builtin_amdgcn_cvt_pkrtz(a, b);
  return cv.u;
}
DEVI float fdot2u(unsigned a, unsigned b, float c) {  // f16 dot2, f32 accum (proven R17)
  union { unsigned u; h2v h; } ca, cb; ca.u = a; cb.u = b;
  return __builtin_amdgcn_fdot2(ca.h, cb.h, c, false);
}
DEVI __half2 uh2(unsigned u) { union { unsigned u; __half2 h; } c; c.u = u; return c.h; }
DEVI void gld16(const void* g, void* l) {
  __builtin_amdgcn_global_load_lds((glb_u32*)g, (lds_u32*)l, 16, 0, 0);
}
DEVI float pairsum(float part) {           // part + part[lane^1], via DPP quad_perm
  int o = __builtin_amdgcn_update_dpp(0, __float_as_int(part), 0xB1, 0xf, 0xf, true);
  return part + __int_as_float(o);
}

// ---------------- prep: transpose + cast weights to bf16 ----------------
__global__ void prep_weights(const float* __restrict__ Wq, const float* __restrict__ Wk,
                             const float* __restrict__ Wv, const float* __restrict__ Wout,
                             short* __restrict__ WcT, short* __restrict__ WoT) {
  int n = blockIdx.x;
  int k = threadIdx.x;
  float v;
  if (n < 256)      v = Wq[k * 256 + n];
  else if (n < 512) v = Wk[k * 256 + (n - 256)];
  else              v = Wv[k * 256 + (n - 512)];
  WcT[n * 256 + k] = f2bf(v);
  if (n < 256) WoT[n * 256 + k] = f2bf(Wout[k * 256 + n]);
}

// ---------------- x -> bf16 cast ----------------
__global__ void x_cast(const float* __restrict__ x, short* __restrict__ xb) {
  for (size_t gidx = (size_t)blockIdx.x * 256 + threadIdx.x; gidx < 4194304;
       gidx += (size_t)4096 * 256) {
    const float4* src = reinterpret_cast<const float4*>(x + gidx * 8);
    float4 a = src[0], c = src[1];
    v8s pk;
    pk[0] = f2bf(a.x); pk[1] = f2bf(a.y); pk[2] = f2bf(a.z); pk[3] = f2bf(a.w);
    pk[4] = f2bf(c.x); pk[5] = f2bf(c.y); pk[6] = f2bf(c.z); pk[7] = f2bf(c.w);
    *reinterpret_cast<v8s*>(xb + gidx * 8) = pk;
  }
}

// ---------------- QKV projection: 256x256 tile, swapped-operand MFMA, wide stores ----------------
// Q/K/V all emitted as packed f16 (attn consumes via fdot2 / hfma2).
__launch_bounds__(512, 2)
__global__ void proj_gemm(const short* __restrict__ xb, const short* __restrict__ WcT,
                          const float* __restrict__ pos_emb,
                          short* __restrict__ Qb, short* __restrict__ Kb,
                          short* __restrict__ Vb) {
  __shared__ short As[2][256 * 64];
  __shared__ short Bs[2][256 * 64];
  const int t = threadIdx.x;
  const int bi = blockIdx.x;
  const int xcd = bi & 7;
  const int j = bi >> 3;               // 0..191
  const int mtl = j / 3, nt = j % 3;
  const int mt = xcd * 64 + mtl;       // 0..511, bijective
  const int m0 = mt * 256, n0 = nt * 256;
  const int wave = t >> 6, lane = t & 63;
  const int wm = (wave >> 2) * 128, wn = (wave & 3) * 64;
  const int lr = lane & 15, g = lane >> 4;

  const int ro = lane >> 3;
  const int colb = ((lane & 7) * 16) ^ (ro << 4);
  const char* aSrc0 = reinterpret_cast<const char*>(xb + (size_t)(m0 + ro) * 256) + colb;
  const char* bSrc0 = reinterpret_cast<const char*>(WcT + (size_t)(n0 + ro) * 256) + colb;

  auto stage = [&](int buf, int ks) {
#pragma unroll
    for (int c = 0; c < 4; ++c) {
      int cc = wave * 4 + c;
      gld16(aSrc0 + (size_t)cc * 8 * 512 + ks * 128, (char*)As[buf] + cc * 1024);
      gld16(bSrc0 + (size_t)cc * 8 * 512 + ks * 128, (char*)Bs[buf] + cc * 1024);
    }
  };

  v4f acc[8][4];
#pragma unroll
  for (int i = 0; i < 8; ++i)
#pragma unroll
    for (int jj = 0; jj < 4; ++jj) acc[i][jj] = (v4f){0.f, 0.f, 0.f, 0.f};

  stage(0, 0);
  __syncthreads();

#pragma unroll 1
  for (int s = 0; s < 4; ++s) {
    const int buf = s & 1;
    if (s < 3) stage(buf ^ 1, s + 1);

    const char* aB = (const char*)As[buf];
    const char* bB = (const char*)Bs[buf];
#pragma unroll
    for (int kk = 0; kk < 2; ++kk) {
      v8s bfr[4];
#pragma unroll
      for (int jj = 0; jj < 4; ++jj) {
        int rn = wn + jj * 16 + lr;
        bfr[jj] = *reinterpret_cast<const v8s*>(
            bB + ((rn * 128 + kk * 64 + g * 16) ^ ((rn & 7) << 4)));
      }
#pragma unroll
      for (int i = 0; i < 8; ++i) {
        int row = wm + i * 16 + lr;
        v8s af = *reinterpret_cast<const v8s*>(
            aB + ((row * 128 + kk * 64 + g * 16) ^ ((row & 7) << 4)));
#pragma unroll
        for (int jj = 0; jj < 4; ++jj)
          acc[i][jj] = __builtin_amdgcn_mfma_f32_16x16x32_bf16(bfr[jj], af, acc[i][jj], 0, 0, 0);
      }
    }
    __syncthreads();
  }

  short* dst = (nt == 0) ? Qb : (nt == 1) ? Kb : Vb;
#pragma unroll
  for (int i = 0; i < 8; ++i) {
    int p = m0 + wm + i * 16 + lr;
    int qi = 0;
    if (nt == 0) {
      int yy = (p >> 7) & 127, xx = p & 127;
      qi = (yy - min(max(yy, 2), 125) + 2) * 5 + (xx - min(max(xx, 2), 125) + 2);
    }
#pragma unroll
    for (int jj = 0; jj < 4; ++jj) {
      int nb = wn + jj * 16 + g * 4;
      v4f a = acc[i][jj];
      if (nt == 0) {
        float4 pe4 = *reinterpret_cast<const float4*>(pos_emb + qi * 256 + nb);
        a[0] += pe4.x; a[1] += pe4.y; a[2] += pe4.z; a[3] += pe4.w;
      }
      uint2 pk;
      pk.x = pkh(a[0], a[1]);
      pk.y = pkh(a[2], a[3]);
      *reinterpret_cast<uint2*>(dst + (size_t)p * 256 + nb) = pk;
    }
  }
}

// ---------------- attention: split-F, all-f16, depth-2 prefetch, DPP pair-sum ----------------
__launch_bounds__(256, 4)
__global__ void attn_kernel(const short* __restrict__ Qb, const short* __restrict__ Kb,
                            const short* __restrict__ Vb, const float* __restrict__ pos_emb,
                            short* __restrict__ ACC) {
  __shared__ unsigned pe16[25 * 128];   // packed f16 pairs, word-swizzled (R20-proven, 0 conflicts)
  for (int i = threadIdx.x; i < 1600; i += 256) {
    float4 vv = reinterpret_cast<const float4*>(pos_emb)[i];
    int s = i >> 6;
    int jw = (i & 63) * 2;
    int e = ((jw >> 5) & 3) << 1;
    uint2 pk2;
    pk2.x = pkh(vv.x, vv.y);
    pk2.y = pkh(vv.z, vv.w);
    *reinterpret_cast<uint2*>(pe16 + s * 128 + (jw ^ e)) = pk2;
  }

  const int t = threadIdx.x;
  const int half = t & 1, h = (t >> 1) & 7, pl = t >> 4;
  const int id = blockIdx.x;
  const int b = id & 7;
  const int local = id >> 3;
  const int bx = local & 31, by = local >> 5;
  const int xx = bx * 4 + (pl & 3);
  const int yy = by * 4 + (pl >> 2);
  const int yc = min(max(yy, 2), 125), xc = min(max(xx, 2), 125);
  const int fo = h * 32 + half * 16;
  const size_t pbase = ((size_t)((b * 128 + yy) * 128 + xx)) * 256 + fo;
  const size_t cbase = ((size_t)((b * 128 + yc) * 128 + xc)) * 256 + fo;
  const float SCALE2 = 0.17677669529663689f * 1.4426950408889634f;  // rsqrt(32)*log2(e)

  uint4 qA = *reinterpret_cast<const uint4*>(Qb + pbase);
  uint4 qB = *reinterpret_cast<const uint4*>(Qb + pbase + 8);
  __syncthreads();

  float l = 0.f;
  __half2 oa[8];
#pragma unroll
  for (int jv = 0; jv < 8; ++jv) oa[jv] = uh2(0u);

  const short* kb = Kb + cbase;
  const short* vb = Vb + cbase;
  const int sw = h * 16 + half * 8;
  const int e = (h >> 1) << 1;

  // depth-2 prefetch: set a = offset s, set b = offset s+1
  uint4 k0a, k1a, v0a, v1a, k0b, k1b, v0b, v1b;
  {
    const short* kp = kb + (-2 * 128 - 2) * 256;
    const short* vp = vb + (-2 * 128 - 2) * 256;
    k0a = *reinterpret_cast<const uint4*>(kp);
    k1a = *reinterpret_cast<const uint4*>(kp + 8);
    v0a = *reinterpret_cast<const uint4*>(vp);
    v1a = *reinterpret_cast<const uint4*>(vp + 8);
    const short* kp1 = kb + (-2 * 128 - 1) * 256;
    const short* vp1 = vb + (-2 * 128 - 1) * 256;
    k0b = *reinterpret_cast<const uint4*>(kp1);
    k1b = *reinterpret_cast<const uint4*>(kp1 + 8);
    v0b = *reinterpret_cast<const uint4*>(vp1);
    v1b = *reinterpret_cast<const uint4*>(vp1 + 8);
  }

#pragma unroll 1
  for (int dy = -2; dy <= 2; ++dy) {
    const unsigned* prow = pe16 + ((dy + 2) * 5) * 128 + sw;
#pragma unroll
    for (int dxi = 0; dxi < 5; ++dxi) {
      const int dx = dxi - 2;
      uint4 k0 = k0a, k1 = k1a, v0 = v0a, v1 = v1a;
      // rotate b -> a
      k0a = k0b; k1a = k1b; v0a = v0b; v1a = v1b;
      // prefetch offset s+2
      int ndx = dx + 2, ndy = dy;
      if (ndx > 2) { ndx -= 5; ndy += 1; }
      if (ndy <= 2) {
        const short* kp2 = kb + (ndy * 128 + ndx) * 256;
        const short* vp2 = vb + (ndy * 128 + ndx) * 256;
        k0b = *reinterpret_cast<const uint4*>(kp2);
        k1b = *reinterpret_cast<const uint4*>(kp2 + 8);
        v0b = *reinterpret_cast<const uint4*>(vp2);
        v1b = *reinterpret_cast<const uint4*>(vp2 + 8);
      }
      const unsigned* ps = prow + dxi * 128;
      uint2 pp0 = *reinterpret_cast<const uint2*>(ps + (0 ^ e));
      uint2 pp1 = *reinterpret_cast<const uint2*>(ps + (2 ^ e));
      uint2 pp2 = *reinterpret_cast<const uint2*>(ps + (4 ^ e));
      uint2 pp3 = *reinterpret_cast<const uint2*>(ps + (6 ^ e));

      float d0 = 0.f, d1 = 0.f, d2 = 0.f, d3 = 0.f;
      d0 = fdot2u(qA.x, k0.x, d0); d1 = fdot2u(qA.y, k0.y, d1);
      d2 = fdot2u(qA.z, k0.z, d2); d3 = fdot2u(qA.w, k0.w, d3);
      d0 = fdot2u(qB.x, k1.x, d0); d1 = fdot2u(qB.y, k1.y, d1);
      d2 = fdot2u(qB.z, k1.z, d2); d3 = fdot2u(qB.w, k1.w, d3);
      d0 = fdot2u(qA.x, pp0.x, d0); d1 = fdot2u(qA.y, pp0.y, d1);
      d2 = fdot2u(qA.z, pp1.x, d2); d3 = fdot2u(qA.w, pp1.y, d3);
      d0 = fdot2u(qB.x, pp2.x, d0); d1 = fdot2u(qB.y, pp2.y, d1);
      d2 = fdot2u(qB.z, pp3.x, d2); d3 = fdot2u(qB.w, pp3.y, d3);

      float part = ((d0 + d1) + (d2 + d3)) * SCALE2;
      float full = pairsum(part);           // DPP quad_perm, no LDS round-trip
      float w = exp2f(full);
      l += w;
      __half2 w2 = uh2(pkh(w, w));
      oa[0] = __hfma2(w2, uh2(v0.x), oa[0]);
      oa[1] = __hfma2(w2, uh2(v0.y), oa[1]);
      oa[2] = __hfma2(w2, uh2(v0.z), oa[2]);
      oa[3] = __hfma2(w2, uh2(v0.w), oa[3]);
      oa[4] = __hfma2(w2, uh2(v1.x), oa[4]);
      oa[5] = __hfma2(w2, uh2(v1.y), oa[5]);
      oa[6] = __hfma2(w2, uh2(v1.z), oa[6]);
      oa[7] = __hfma2(w2, uh2(v1.w), oa[7]);
    }
  }

  float inv = 1.f / l;
  uint4 s0, s1;
  s0.x = cvtpk(__low2float(oa[0]) * inv, __high2float(oa[0]) * inv);
  s0.y = cvtpk(__low2float(oa[1]) * inv, __high2float(oa[1]) * inv);
  s0.z = cvtpk(__low2float(oa[2]) * inv, __high2float(oa[2]) * inv);
  s0.w = cvtpk(__low2float(oa[3]) * inv, __high2float(oa[3]) * inv);
  s1.x = cvtpk(__low2float(oa[4]) * inv, __high2float(oa[4]) * inv);
  s1.y = cvtpk(__low2float(oa[5]) * inv, __high2float(oa[5]) * inv);
  s1.z = cvtpk(__low2float(oa[6]) * inv, __high2float(oa[6]) * inv);
  s1.w = cvtpk(__low2float(oa[7]) * inv, __high2float(oa[7]) * inv);
  *reinterpret_cast<uint4*>(ACC + pbase) = s0;
  *reinterpret_cast<uint4*>(ACC + pbase + 8) = s1;
}

// ---------------- output projection: 256x256 tile, swapped operands, float4 stores ----------------
__launch_bounds__(512, 2)
__global__ void out_gemm(const short* __restrict__ A, const short* __restrict__ WoT,
                         float* __restrict__ out) {
  __shared__ short As[2][256 * 64];
  __shared__ short Bs[2][256 * 64];
  const int t = threadIdx.x;
  const int bi = blockIdx.x;
  const int xcd = bi & 7;
  const int mt = xcd * 64 + (bi >> 3);
  const int m0 = mt * 256;
  const int wave = t >> 6, lane = t & 63;
  const int wm = (wave >> 2) * 128, wn = (wave & 3) * 64;
  const int lr = lane & 15, g = lane >> 4;

  const int ro = lane >> 3;
  const int colb = ((lane & 7) * 16) ^ (ro << 4);
  const char* aSrc0 = reinterpret_cast<const char*>(A + (size_t)(m0 + ro) * 256) + colb;
  const char* bSrc0 = reinterpret_cast<const char*>(WoT + (size_t)ro * 256) + colb;

  auto stage = [&](int buf, int ks) {
#pragma unroll
    for (int c = 0; c < 4; ++c) {
      int cc = wave * 4 + c;
      gld16(aSrc0 + (size_t)cc * 8 * 512 + ks * 128, (char*)As[buf] + cc * 1024);
      gld16(bSrc0 + (size_t)cc * 8 * 512 + ks * 128, (char*)Bs[buf] + cc * 1024);
    }
  };

  v4f acc[8][4];
#pragma unroll
  for (int i = 0; i < 8; ++i)
#pragma unroll
    for (int jj = 0; jj < 4; ++jj) acc[i][jj] = (v4f){0.f, 0.f, 0.f, 0.f};

  stage(0, 0);
  __syncthreads();

#pragma unroll 1
  for (int s = 0; s < 4; ++s) {
    const int buf = s & 1;
    if (s < 3) stage(buf ^ 1, s + 1);

    const char* aB = (const char*)As[buf];
    const char* bB = (const char*)Bs[buf];
#pragma unroll
    for (int kk = 0; kk < 2; ++kk) {
      v8s bfr[4];
#pragma unroll
      for (int jj = 0; jj < 4; ++jj) {
        int rn = wn + jj * 16 + lr;
        bfr[jj] = *reinterpret_cast<const v8s*>(
            bB + ((rn * 128 + kk * 64 + g * 16) ^ ((rn & 7) << 4)));
      }
#pragma unroll
      for (int i = 0; i < 8; ++i) {
        int row = wm + i * 16 + lr;
        v8s af = *reinterpret_cast<const v8s*>(
            aB + ((row * 128 + kk * 64 + g * 16) ^ ((row & 7) << 4)));
#pragma unroll
        for (int jj = 0; jj < 4; ++jj)
          acc[i][jj] = __builtin_amdgcn_mfma_f32_16x16x32_bf16(bfr[jj], af, acc[i][jj], 0, 0, 0);
      }
    }
    __syncthreads();
  }

#pragma unroll
  for (int i = 0; i < 8; ++i) {
    int p = m0 + wm + i * 16 + lr;
#pragma unroll
    for (int jj = 0; jj < 4; ++jj) {
      int nb = wn + jj * 16 + g * 4;
      float4 o;
      o.x = acc[i][jj][0]; o.y = acc[i][jj][1];
      o.z = acc[i][jj][2]; o.w = acc[i][jj][3];
      *reinterpret_cast<float4*>(out + (size_t)p * 256 + nb) = o;
    }
  }
}

extern "C" void kernel_launch(void* const* d_in, const int* in_sizes, int n_in,
                              void* d_out, int out_size, void* d_ws, size_t ws_size,
                              hipStream_t stream) {
  const float* x       = (const float*)d_in[0];
  const float* Wq      = (const float*)d_in[1];
  const float* Wk      = (const float*)d_in[2];
  const float* Wv      = (const float*)d_in[3];
  const float* Wout    = (const float*)d_in[4];
  const float* pos_emb = (const float*)d_in[5];
  float* out = (float*)d_out;

  char* ws = (char*)d_ws;
  short* WcT  = (short*)ws;                       // 768*256*2   = 393216 B
  short* WoT  = (short*)(ws + 393216);            // 256*256*2   = 131072 B
  short* Qb   = (short*)(ws + 524288);            // 131072*256*2 each
  short* Kb   = Qb + (size_t)131072 * 256;
  short* Vb   = Kb + (size_t)131072 * 256;
  short* ACCb = Vb + (size_t)131072 * 256;
  short* xb   = ACCb;   // alias: xb used only before attn writes ACCb

  prep_weights<<<768, 256, 0, stream>>>(Wq, Wk, Wv, Wout, WcT, WoT);
  x_cast<<<4096, 256, 0, stream>>>(x, xb);
  proj_gemm<<<1536, 512, 0, stream>>>(xb, WcT, pos_emb, Qb, Kb, Vb);
  attn_kernel<<<8192, 256, 0, stream>>>(Qb, Kb, Vb, pos_emb, ACCb);
  out_gemm<<<512, 512, 0, stream>>>(ACCb, WoT, out);
}